// Round 5
// baseline (241.505 us; speedup 1.0000x reference)
//
#include <hip/hip_runtime.h>
#include <hip/hip_bf16.h>

// EdgeNet fused 2-layer MLP, MI355X (gfx950) — round 5.
//
// R4 post-mortem: WRITE_SIZE 365 MB vs 200 MB out => ~165 MB scratch spills.
// The 64-reg c[16] prefetch at VGPR cap 128 spilled; T14 became a scratch
// round-trip. R5 halves every footprint so prefetch+acc fit in 128 regs:
//   tile 64 rows, 8 waves; prefetch = 8 f32x4/lane (32 regs); acc = 32 regs.
//   Separate 32 KiB h buffer -> 2 barriers/tile; prefetch issued at stage time
//   stays in flight across the whole tile. LDS 67 KiB -> 2 blocks/CU.
//
// MFMA conventions (verified R1/R2/R4, absmax 0.031):
//   A-frag: lane holds A[row = lane&15][k = 8*(lane>>4)+i], i=0..7
//   B-frag: lane holds B[k = 8*(lane>>4)+i][col = lane&15]
//   C/D  : lane holds C[row = 4*(lane>>4)+reg][col = lane&15]
//
// Per-tile wave roles (w = 0..7, lane: m16 = lane&15, g = lane>>4):
//   stage: wave w loads child rows [16*(w>>1), +16), k-half (w&1)*128..+128
//          -> bf16 x-frags (mf = w>>1, kt' = (w&1)*4 + kt), LDS lane' == lane.
//   compute: wave w owns output n-slice [32w, 32w+32) in BOTH layers.

typedef float f32x4 __attribute__((ext_vector_type(4)));
typedef short bf16x8 __attribute__((ext_vector_type(8)));
typedef unsigned int u32;
typedef u32 u32x4 __attribute__((ext_vector_type(4)));

__device__ __forceinline__ u32 pk2bf(float a, float b) {
    __hip_bfloat162 h2 = __float22bfloat162_rn(make_float2(a, b));
    u32 r;
    __builtin_memcpy(&r, &h2, 4);
    return r;
}

// Pack W (torch layout [n][k] row-major, f32) into per-lane MFMA fragment order:
// halfword[((kt*16 + nt)*64 + lane)*8 + i] = bf16(W[nt*16 + (lane&15)][kt*32 + 8*(lane>>4) + i])
__global__ __launch_bounds__(256) void pack_w_kernel(
    const float* __restrict__ W1, const float* __restrict__ W2,
    unsigned short* __restrict__ wp)
{
    int t = blockIdx.x * 256 + threadIdx.x;   // 0..16383
    int sel = t >> 13;
    int tt = t & 8191;
    int lane = tt & 63;
    int nt = (tt >> 6) & 15;
    int kt = tt >> 10;
    int n = nt * 16 + (lane & 15);
    int k0 = kt * 32 + 8 * (lane >> 4);
    const float* W = sel ? W2 : W1;
    const float* src = W + n * 256 + k0;
    f32x4 a = *(const f32x4*)src;
    f32x4 b = *(const f32x4*)(src + 4);
    u32x4 d;
    d.x = pk2bf(a.x, a.y);
    d.y = pk2bf(a.z, a.w);
    d.z = pk2bf(b.x, b.y);
    d.w = pk2bf(b.z, b.w);
    *(u32x4*)(wp + (size_t)t * 8) = d;
}

__global__ __launch_bounds__(512, 4) void fused_mlp(
    const float* __restrict__ child, const float* __restrict__ parent,
    const float* __restrict__ b1, const float* __restrict__ b2,
    const unsigned short* __restrict__ w1p, const unsigned short* __restrict__ w2p,
    float* __restrict__ out, int n_rows)
{
    // x-frags: frag (mf, kt) at halfword (mf*8+kt)*512 + lane*8   (mf<4, kt<8)
    __shared__ __align__(16) unsigned short xf[16384];   // 32 KiB
    __shared__ __align__(16) unsigned short hf[16384];   // 32 KiB h-frags
    __shared__ __align__(16) float par[256];
    __shared__ __align__(16) float bias[512];            // [0..255]=b1, [256..511]=b2

    const int tid = threadIdx.x;
    const int lane = tid & 63;
    const int w = tid >> 6;        // wave 0..7
    const int m16 = lane & 15;
    const int g = lane >> 4;
    const int mfS = w >> 1;        // stage: this wave's 16-row group
    const int khalf = (w & 1) * 128;

    if (tid < 256) { par[tid] = parent[tid]; bias[tid] = b1[tid]; }
    else           { bias[tid] = b2[tid - 256]; }
    __syncthreads();

    const int n_tiles = (n_rows + 63) >> 6;    // 3125 (exact: 200000 = 64*3125)

    // ---- T14 prefetch: 8 f32x4/lane = this wave's share of next tile ----
    f32x4 c[8];
    auto issue = [&](int tile) {
        long row = (long)tile * 64 + mfS * 16 + m16;
        long lim = (long)n_rows - 1;
        if (row > lim) row = lim;              // clamp: harmless duplicate reads
        const float* cp = child + row * 256 + khalf + 8 * g;
        #pragma unroll
        for (int kt = 0; kt < 4; ++kt) {
            c[2 * kt]     = *(const f32x4*)(cp + kt * 32);
            c[2 * kt + 1] = *(const f32x4*)(cp + kt * 32 + 4);
        }
    };

    issue(blockIdx.x);

    for (int tile = blockIdx.x; tile < n_tiles; tile += gridDim.x) {
        const int row0 = tile * 64;

        // ---- stage: parent-mul, bf16 pack, x-frag write (lane'==lane) ----
        #pragma unroll
        for (int kt = 0; kt < 4; ++kt) {
            const int k0 = khalf + kt * 32 + 8 * g;
            f32x4 p0 = *(const f32x4*)&par[k0];
            f32x4 p1 = *(const f32x4*)&par[k0 + 4];
            f32x4 c0 = c[2 * kt] * p0;
            f32x4 c1 = c[2 * kt + 1] * p1;
            u32x4 u;
            u.x = pk2bf(c0.x, c0.y);
            u.y = pk2bf(c0.z, c0.w);
            u.z = pk2bf(c1.x, c1.y);
            u.w = pk2bf(c1.z, c1.w);
            const int ktp = (w & 1) * 4 + kt;
            *(u32x4*)&xf[((mfS * 8 + ktp) * 64 + lane) * 8] = u;
        }
        // ---- issue next tile's loads: in flight across the whole tile ----
        issue(tile + gridDim.x);
        __syncthreads();                       // BAR1: x-frags visible

        // ---- layer 1: wave w computes n-slice [32w, 32w+32) ----
        f32x4 acc1[2][4];
        #pragma unroll
        for (int j = 0; j < 2; ++j) {
            f32x4 bv = *(const f32x4*)&bias[(2 * w + j) * 16 + 4 * g];
            #pragma unroll
            for (int mf = 0; mf < 4; ++mf) acc1[j][mf] = bv;
        }
        #pragma unroll
        for (int kt = 0; kt < 8; ++kt) {
            bf16x8 a0 = *(const bf16x8*)(w1p + (size_t)((kt * 16 + 2 * w) * 64 + lane) * 8);
            bf16x8 a1 = *(const bf16x8*)(w1p + (size_t)((kt * 16 + 2 * w + 1) * 64 + lane) * 8);
            #pragma unroll
            for (int mf = 0; mf < 4; ++mf) {
                bf16x8 bfrag = *(const bf16x8*)&xf[((mf * 8 + kt) * 64 + lane) * 8];
                acc1[0][mf] = __builtin_amdgcn_mfma_f32_16x16x32_bf16(a0, bfrag, acc1[0][mf], 0, 0, 0);
                acc1[1][mf] = __builtin_amdgcn_mfma_f32_16x16x32_bf16(a1, bfrag, acc1[1][mf], 0, 0, 0);
            }
        }

        // ---- relu + pack h -> h-frags (kt2 = w) ----
        // lane holds h[k2 = 32w + 16j + 4g + r][m = mf*16 + m16]
        //   -> frag (mf, w), lane' = 16*(2j + (g>>1)) + m16, halfword 4*(g&1) + r
        #pragma unroll
        for (int j = 0; j < 2; ++j) {
            #pragma unroll
            for (int mf = 0; mf < 4; ++mf) {
                f32x4 v = acc1[j][mf];
                v.x = fmaxf(v.x, 0.0f); v.y = fmaxf(v.y, 0.0f);
                v.z = fmaxf(v.z, 0.0f); v.w = fmaxf(v.w, 0.0f);
                u32* dst = (u32*)&hf[((mf * 8 + w) * 64 + 16 * (2 * j + (g >> 1)) + m16) * 8 + 4 * (g & 1)];
                dst[0] = pk2bf(v.x, v.y);
                dst[1] = pk2bf(v.z, v.w);
            }
        }
        __syncthreads();                       // BAR2: h-frags visible; xf reads done

        // ---- layer 2 + epilogue ----
        f32x4 acc2[2][4];
        #pragma unroll
        for (int j = 0; j < 2; ++j) {
            f32x4 bv = *(const f32x4*)&bias[256 + (2 * w + j) * 16 + 4 * g];
            #pragma unroll
            for (int mf = 0; mf < 4; ++mf) acc2[j][mf] = bv;
        }
        #pragma unroll
        for (int kt = 0; kt < 8; ++kt) {
            bf16x8 a0 = *(const bf16x8*)(w2p + (size_t)((kt * 16 + 2 * w) * 64 + lane) * 8);
            bf16x8 a1 = *(const bf16x8*)(w2p + (size_t)((kt * 16 + 2 * w + 1) * 64 + lane) * 8);
            #pragma unroll
            for (int mf = 0; mf < 4; ++mf) {
                bf16x8 hfrag = *(const bf16x8*)&hf[((mf * 8 + kt) * 64 + lane) * 8];
                acc2[0][mf] = __builtin_amdgcn_mfma_f32_16x16x32_bf16(a0, hfrag, acc2[0][mf], 0, 0, 0);
                acc2[1][mf] = __builtin_amdgcn_mfma_f32_16x16x32_bf16(a1, hfrag, acc2[1][mf], 0, 0, 0);
            }
        }

        // store: lane holds out[m = mf*16+m16][n2 = (2w+j)*16 + 4g + r]
        #pragma unroll
        for (int mf = 0; mf < 4; ++mf) {
            if (row0 + mf * 16 < n_rows) {     // wave-uniform
                float* orow = out + (size_t)(row0 + mf * 16 + m16) * 256 + 4 * g;
                #pragma unroll
                for (int j = 0; j < 2; ++j) {
                    f32x4 v = acc2[j][mf];
                    v.x = fmaxf(v.x, 0.0f); v.y = fmaxf(v.y, 0.0f);
                    v.z = fmaxf(v.z, 0.0f); v.w = fmaxf(v.w, 0.0f);
                    *(f32x4*)(orow + (2 * w + j) * 16) = v;
                }
            }
        }
        // next iteration's stage writes xf (BAR2 guarantees all xf reads done);
        // next iteration's hf writes happen only after its BAR1 (all D reads done).
    }
}

extern "C" void kernel_launch(void* const* d_in, const int* in_sizes, int n_in,
                              void* d_out, int out_size, void* d_ws, size_t ws_size,
                              hipStream_t stream) {
    const float* parent = (const float*)d_in[0];
    const float* child  = (const float*)d_in[1];
    const float* W1     = (const float*)d_in[2];
    const float* b1     = (const float*)d_in[3];
    const float* W2     = (const float*)d_in[4];
    const float* b2     = (const float*)d_in[5];
    float* out = (float*)d_out;

    unsigned short* wp = (unsigned short*)d_ws;   // [0..65535]=W1 frags, [65536..131071]=W2 frags
    const int n_rows = in_sizes[1] / 256;         // 200000

    pack_w_kernel<<<64, 256, 0, stream>>>(W1, W2, wp);
    fused_mlp<<<512, 512, 0, stream>>>(child, parent, b1, b2,
                                       wp, wp + 65536, out, n_rows);
}

// Round 6
// 120.682 us; speedup vs baseline: 2.0012x; 2.0012x over previous
//
#include <hip/hip_runtime.h>
#include <hip/hip_bf16.h>

// EdgeNet fused 2-layer MLP, MI355X (gfx950) — round 6.
//
// out[m][n2] = relu( W2 · relu( W1 · (parent ⊙ child[m]) + b1 ) + b2 )
//
// R4/R5 post-mortem: VGPR-resident tile prefetch ALWAYS spills (WRITE_SIZE
// 365/482 MB vs 200 MB out). R6 removes every persistent VGPR array:
//  * parent folded into W1 in pack kernel: W1'[n][k] = W1[n][k]*parent[k],
//    so the hot path consumes RAW child f32 — no parent-mul, no x-frag stage.
//  * child tile staged via global_load_lds (no VGPR transit, no spill);
//    tile t+1 issued right after the mid-tile barrier -> in flight across
//    layer2 + store + next layer1.
//  * T2 XOR-swizzle (units of 16 B, unit ^= row&7) applied on the GLOBAL
//    source address (gload_lds dest must stay linear, rule #21) and mirrored
//    on the LDS read side -> 2 lanes/bank (free) instead of 16-way.
// LDS: 64 KiB child + 32 KiB h-frags + 2 KiB bias = 98 KiB -> 1 block/CU.
// 2 barriers/tile. Registers uncapped (no launch_bounds min-occupancy arg!).
//
// MFMA conventions (verified R1..R5, absmax 0.031):
//   A-frag: lane holds A[row = lane&15][k = 8*(lane>>4)+i], i=0..7
//   B-frag: lane holds B[k = 8*(lane>>4)+i][col = lane&15]
//   C/D  : lane holds C[row = 4*(lane>>4)+reg][col = lane&15]
// Compute: wave w owns output n-slice [32w, 32w+32) in BOTH layers.

typedef float f32x4 __attribute__((ext_vector_type(4)));
typedef short bf16x8 __attribute__((ext_vector_type(8)));
typedef unsigned int u32;
typedef u32 u32x4 __attribute__((ext_vector_type(4)));

__device__ __forceinline__ u32 pk2bf(float a, float b) {
    __hip_bfloat162 h2 = __float22bfloat162_rn(make_float2(a, b));
    u32 r;
    __builtin_memcpy(&r, &h2, 4);
    return r;
}

// Pack weights into per-lane MFMA A-fragment order; parent folded into W1.
// halfword[((kt*16 + nt)*64 + lane)*8 + i] = bf16(W'[nt*16 + (lane&15)][kt*32 + 8*(lane>>4) + i])
__global__ __launch_bounds__(256) void pack_w_kernel(
    const float* __restrict__ W1, const float* __restrict__ W2,
    const float* __restrict__ parent, unsigned short* __restrict__ wp)
{
    int t = blockIdx.x * 256 + threadIdx.x;   // 0..16383
    int sel = t >> 13;
    int tt = t & 8191;
    int lane = tt & 63;
    int nt = (tt >> 6) & 15;
    int kt = tt >> 10;
    int n = nt * 16 + (lane & 15);
    int k0 = kt * 32 + 8 * (lane >> 4);
    const float* W = sel ? W2 : W1;
    const float* src = W + n * 256 + k0;
    f32x4 a = *(const f32x4*)src;
    f32x4 b = *(const f32x4*)(src + 4);
    if (sel == 0) {                            // fold parent into W1
        a *= *(const f32x4*)(parent + k0);
        b *= *(const f32x4*)(parent + k0 + 4);
    }
    u32x4 d;
    d.x = pk2bf(a.x, a.y);
    d.y = pk2bf(a.z, a.w);
    d.z = pk2bf(b.x, b.y);
    d.w = pk2bf(b.z, b.w);
    *(u32x4*)(wp + (size_t)t * 8) = d;
}

__global__ __launch_bounds__(512) void fused_mlp(
    const float* __restrict__ child,
    const float* __restrict__ b1, const float* __restrict__ b2,
    const unsigned short* __restrict__ w1p, const unsigned short* __restrict__ w2p,
    float* __restrict__ out, int n_rows)
{
    // child tile: row r occupies f32 [r*256, r*256+256); 16B-unit u within the
    // row is stored at physical unit u ^ (r&7)  (involution, rule #21).
    __shared__ __align__(16) float craw[16384];          // 64 KiB
    __shared__ __align__(16) unsigned short hf[16384];   // 32 KiB h-frags
    __shared__ __align__(16) float bias[512];            // [0..255]=b1, [256..511]=b2

    const int tid = threadIdx.x;
    const int lane = tid & 63;
    const int w = tid >> 6;        // wave 0..7
    const int m16 = lane & 15;
    const int g = lane >> 4;
    const int s = m16 & 7;         // read-side unswizzle key

    if (tid < 256) bias[tid] = b1[tid];
    else           bias[tid] = b2[tid - 256];

    const int n_tiles = (n_rows + 63) >> 6;    // 3125 (200000 = 64*3125)

    // Stage one 64-row tile: wave w loads rows 8w..8w+7, one gload_lds (1 KiB,
    // 16 B/lane) per row. Global src pre-swizzled so LDS layout = unit^(r&7).
    auto issue = [&](int tile) {
        #pragma unroll
        for (int j = 0; j < 8; ++j) {
            const int r = w * 8 + j;
            long row = (long)tile * 64 + r;
            long lim = (long)n_rows - 1;
            if (row > lim) row = lim;          // clamp: harmless duplicate read
            const float* gsrc = child + row * 256 + ((lane ^ (r & 7)) << 2);
            float* ldst = &craw[r * 256];      // wave-uniform base, lane*16B dest
            __builtin_amdgcn_global_load_lds(
                (const __attribute__((address_space(1))) void*)gsrc,
                (__attribute__((address_space(3))) void*)ldst,
                16, 0, 0);
        }
    };

    if (blockIdx.x < n_tiles) issue(blockIdx.x);
    __syncthreads();                           // BAR0: bias + first tile ready

    for (int tile = blockIdx.x; tile < n_tiles; tile += gridDim.x) {
        const int row0 = tile * 64;

        // ---- layer 1: wave w computes n-slice [32w, 32w+32) ----
        f32x4 acc1[2][4];
        #pragma unroll
        for (int j = 0; j < 2; ++j) {
            f32x4 bv = *(const f32x4*)&bias[(2 * w + j) * 16 + 4 * g];
            #pragma unroll
            for (int mf = 0; mf < 4; ++mf) acc1[j][mf] = bv;
        }
        #pragma unroll
        for (int kt = 0; kt < 8; ++kt) {
            bf16x8 a0 = *(const bf16x8*)(w1p + (size_t)((kt * 16 + 2 * w) * 64 + lane) * 8);
            bf16x8 a1 = *(const bf16x8*)(w1p + (size_t)((kt * 16 + 2 * w + 1) * 64 + lane) * 8);
            const int q0 = kt * 8 + 2 * g;     // logical 16B-unit of k=kt*32+8g
            #pragma unroll
            for (int mf = 0; mf < 4; ++mf) {
                const f32x4* rowp = (const f32x4*)&craw[(mf * 16 + m16) * 256];
                f32x4 c0 = rowp[q0 ^ s];
                f32x4 c1 = rowp[(q0 + 1) ^ s];
                u32x4 u;
                u.x = pk2bf(c0.x, c0.y);
                u.y = pk2bf(c0.z, c0.w);
                u.z = pk2bf(c1.x, c1.y);
                u.w = pk2bf(c1.z, c1.w);
                bf16x8 bfrag = __builtin_bit_cast(bf16x8, u);
                acc1[0][mf] = __builtin_amdgcn_mfma_f32_16x16x32_bf16(a0, bfrag, acc1[0][mf], 0, 0, 0);
                acc1[1][mf] = __builtin_amdgcn_mfma_f32_16x16x32_bf16(a1, bfrag, acc1[1][mf], 0, 0, 0);
            }
        }

        // ---- relu + pack h -> h-frags (kt2 = w) ----
        // lane holds h[k2 = 32w + 16j + 4g + r][m = mf*16 + m16]
        //   -> frag (mf, w), lane' = 16*(2j + (g>>1)) + m16, halfword 4*(g&1) + r
        #pragma unroll
        for (int j = 0; j < 2; ++j) {
            #pragma unroll
            for (int mf = 0; mf < 4; ++mf) {
                f32x4 v = acc1[j][mf];
                v.x = fmaxf(v.x, 0.0f); v.y = fmaxf(v.y, 0.0f);
                v.z = fmaxf(v.z, 0.0f); v.w = fmaxf(v.w, 0.0f);
                u32* dst = (u32*)&hf[((mf * 8 + w) * 64 + 16 * (2 * j + (g >> 1)) + m16) * 8 + 4 * (g & 1)];
                dst[0] = pk2bf(v.x, v.y);
                dst[1] = pk2bf(v.z, v.w);
            }
        }
        __syncthreads();                       // BAR2: h-frags ready; craw reads done

        // ---- prefetch next tile into craw (in flight across L2 + store) ----
        {
            const int nxt = tile + gridDim.x;
            if (nxt < n_tiles) issue(nxt);
        }

        // ---- layer 2 + epilogue ----
        f32x4 acc2[2][4];
        #pragma unroll
        for (int j = 0; j < 2; ++j) {
            f32x4 bv = *(const f32x4*)&bias[256 + (2 * w + j) * 16 + 4 * g];
            #pragma unroll
            for (int mf = 0; mf < 4; ++mf) acc2[j][mf] = bv;
        }
        #pragma unroll
        for (int kt = 0; kt < 8; ++kt) {
            bf16x8 a0 = *(const bf16x8*)(w2p + (size_t)((kt * 16 + 2 * w) * 64 + lane) * 8);
            bf16x8 a1 = *(const bf16x8*)(w2p + (size_t)((kt * 16 + 2 * w + 1) * 64 + lane) * 8);
            #pragma unroll
            for (int mf = 0; mf < 4; ++mf) {
                bf16x8 hfrag = *(const bf16x8*)&hf[((mf * 8 + kt) * 64 + lane) * 8];
                acc2[0][mf] = __builtin_amdgcn_mfma_f32_16x16x32_bf16(a0, hfrag, acc2[0][mf], 0, 0, 0);
                acc2[1][mf] = __builtin_amdgcn_mfma_f32_16x16x32_bf16(a1, hfrag, acc2[1][mf], 0, 0, 0);
            }
        }

        // store: lane holds out[m = mf*16+m16][n2 = (2w+j)*16 + 4g + r]
        #pragma unroll
        for (int mf = 0; mf < 4; ++mf) {
            if (row0 + mf * 16 < n_rows) {     // wave-uniform
                float* orow = out + (size_t)(row0 + mf * 16 + m16) * 256 + 4 * g;
                #pragma unroll
                for (int j = 0; j < 2; ++j) {
                    f32x4 v = acc2[j][mf];
                    v.x = fmaxf(v.x, 0.0f); v.y = fmaxf(v.y, 0.0f);
                    v.z = fmaxf(v.z, 0.0f); v.w = fmaxf(v.w, 0.0f);
                    *(f32x4*)(orow + (2 * w + j) * 16) = v;
                }
            }
        }
        __syncthreads();                       // BAR1: craw(t+1) ready (vmcnt(0));
                                               // hf reads done before next write
    }
}

extern "C" void kernel_launch(void* const* d_in, const int* in_sizes, int n_in,
                              void* d_out, int out_size, void* d_ws, size_t ws_size,
                              hipStream_t stream) {
    const float* parent = (const float*)d_in[0];
    const float* child  = (const float*)d_in[1];
    const float* W1     = (const float*)d_in[2];
    const float* b1     = (const float*)d_in[3];
    const float* W2     = (const float*)d_in[4];
    const float* b2     = (const float*)d_in[5];
    float* out = (float*)d_out;

    unsigned short* wp = (unsigned short*)d_ws;   // [0..65535]=W1' frags, [65536..131071]=W2 frags
    const int n_rows = in_sizes[1] / 256;         // 200000

    pack_w_kernel<<<64, 256, 0, stream>>>(W1, W2, parent, wp);

    const int n_tiles = (n_rows + 63) >> 6;
    const int grid = n_tiles < 256 ? n_tiles : 256;
    fused_mlp<<<grid, 512, 0, stream>>>(child, b1, b2,
                                        wp, wp + 65536, out, n_rows);
}